// Round 9
// baseline (187.483 us; speedup 1.0000x reference)
//
#include <hip/hip_runtime.h>

#define N_ITER 100

typedef float f32x4 __attribute__((ext_vector_type(4)));
typedef unsigned u32x4 __attribute__((ext_vector_type(4)));

// RNE-pack two f32 into a dword of two bf16 (proven R7-R16: absmax 3.9e-3).
__device__ __forceinline__ unsigned bf16pack(float a, float b) {
  unsigned ua = __float_as_uint(a), ub = __float_as_uint(b);
  ua = (ua + 0x7FFFu + ((ua >> 16) & 1u)) >> 16;
  ub = (ub + 0x7FFFu + ((ub >> 16) & 1u)) >> 16;
  return ua | (ub << 16);
}
__device__ __forceinline__ float bflo(unsigned u) { return __uint_as_float(u << 16); }
__device__ __forceinline__ float bfhi(unsigned u) { return __uint_as_float(u & 0xFFFF0000u); }

// Force a value's virtual register into AGPR class AT DEFINITION (proven R13:
// kills the accvgpr copy tax; R6 re-proved it -- intrinsic version spilled to
// scratch, +3.7MB HBM round-trip, +23us).
__device__ __forceinline__ void pin_agpr(u32x4& x) {
  asm("" : "=a"(x) : "0"(x));
}

// MFMA with A + accumulator pinned to AGPRs, B in VGPRs (proven R13/R17).
__device__ __forceinline__ void mfma_first(f32x4& acc, const u32x4& a, const u32x4& b) {
  asm("s_nop 2\n\tv_mfma_f32_16x16x32_bf16 %0, %1, %2, 0"
      : "=&a"(acc) : "a"(a), "v"(b));
}
__device__ __forceinline__ void mfma_aa(f32x4& acc, const u32x4& a, const u32x4& b) {
  asm("v_mfma_f32_16x16x32_bf16 %0, %1, %2, %0"
      : "+a"(acc) : "a"(a), "v"(b));
}
__device__ __forceinline__ void mfma_fence(f32x4& acc0, f32x4& acc1) {
  asm volatile("s_nop 7\n\ts_nop 7\n\ts_nop 7" : "+a"(acc0), "+a"(acc1));
}

// Champion R0 structure (123us/dispatch; R1-R3/R5/R6 proved every schedule
// restructure regresses -- the loop is at its cycle floor). R8 proved the
// clock is pinned ~700MHz in this container (full-chip MFMA heater did not
// move it; MfmaUtil-derived heater runtime => ~670-700MHz). Remaining lever:
// PHASE COUNT. The reference's torch original early-exits once converged;
// converged iterations are identity. In bf16 this is exact: once the packed
// R and C vectors are bitwise unchanged across an iteration, all later
// iterations are bit-identical -> break with bit-identical output.
// Detection: each phase all lanes broadcast-read the wave's OLD packed
// scales (issued with the B-loads, off the critical path), compare with the
// new pack; __all -> per-wave flag byte before phase2's barrier; phase1 of
// the next iteration reads the 8 flags and breaks when all set. A peeled
// finalize iteration (identity when converged) writes the f32 scales.
__global__ __launch_bounds__(512)
__attribute__((amdgpu_waves_per_eu(2, 2)))
void sinkhorn_mfma8c(const float* __restrict__ alpha, float* __restrict__ out) {
  __shared__ alignas(16) unsigned short Cb16[256];
  __shared__ alignas(16) unsigned short Rb16[256];
  __shared__ alignas(16) float Cb32[256];
  __shared__ alignas(16) float Rb32[256];
  __shared__ alignas(8) unsigned Fl[2];  // 8 per-wave convergence flag bytes

  const int tid  = threadIdx.x;
  const int lane = tid & 63;
  const int w    = tid >> 6;   // wave 0..7
  const int m    = lane & 15;
  const int q    = lane >> 4;

  const size_t mbase = (size_t)blockIdx.x * (256 * 256);
  const float* A = alpha + mbase;
  float*       O = out + mbase;

  // arow[s][c] elem j <-> V0[32w+16s+m][32c+8q+j]
  // acol[s][c] elem j <-> V0[32c+8q+j][32w+16s+m]
  u32x4 arow[2][8];
  u32x4 acol[2][8];

#pragma unroll
  for (int s = 0; s < 2; ++s) {
    const float* rowp = A + (size_t)(32 * w + 16 * s + m) * 256 + 8 * q;
#pragma unroll
    for (int c = 0; c < 8; ++c) {
      float4 x0 = *(const float4*)(rowp + 32 * c);
      float4 x1 = *(const float4*)(rowp + 32 * c + 4);
      arow[s][c] = (u32x4){bf16pack(__expf(x0.x * 10.0f), __expf(x0.y * 10.0f)),
                           bf16pack(__expf(x0.z * 10.0f), __expf(x0.w * 10.0f)),
                           bf16pack(__expf(x1.x * 10.0f), __expf(x1.y * 10.0f)),
                           bf16pack(__expf(x1.z * 10.0f), __expf(x1.w * 10.0f))};
    }
    const float* colp = A + (size_t)(8 * q) * 256 + 32 * w + 16 * s + m;
#pragma unroll
    for (int c = 0; c < 8; ++c) {
      const float* p = colp + (size_t)(32 * c) * 256;
      acol[s][c] =
          (u32x4){bf16pack(__expf(p[0] * 10.0f), __expf(p[256] * 10.0f)),
                  bf16pack(__expf(p[512] * 10.0f), __expf(p[768] * 10.0f)),
                  bf16pack(__expf(p[1024] * 10.0f), __expf(p[1280] * 10.0f)),
                  bf16pack(__expf(p[1536] * 10.0f), __expf(p[1792] * 10.0f))};
    }
  }
  // Pin all persistent fragments into AGPRs (one-time, far from MFMAs).
#pragma unroll
  for (int s = 0; s < 2; ++s)
#pragma unroll
    for (int c = 0; c < 8; ++c) {
      pin_agpr(arow[s][c]);
      pin_agpr(acol[s][c]);
    }

  if (tid < 256) {
    Cb16[tid] = 0x3F80;  // C = 1
    Rb16[tid] = 0;       // packed scales are never 0 -> first compare fails
  }
  if (tid < 2) Fl[tid] = 0;
  __syncthreads();

  for (int it = 0; it < N_ITER - 1; ++it) {
    // Convergence flags from the previous iteration's phase 2.
    {
      uint2 fl = *(const uint2*)Fl;
      if (fl.x == 0x01010101u && fl.y == 0x01010101u) break;
    }
    bool rsame = true, csame = true;

    // ---------- phase 1: s = V0_rowslabs · C ; R = 1/s ----------
    {
      u32x4 B[8];
#pragma unroll
      for (int c = 0; c < 8; ++c) B[c] = *(const u32x4*)&Cb16[32 * c + 8 * q];
      // Old packed R for the fixed-point check (broadcast, off critical path).
      uint2 oldR0 = *(const uint2*)&Rb16[32 * w + 4 * q];
      uint2 oldR1 = *(const uint2*)&Rb16[32 * w + 16 + 4 * q];
      f32x4 acc0, acc1;
      mfma_first(acc0, arow[0][0], B[0]);
      mfma_first(acc1, arow[1][0], B[0]);
#pragma unroll
      for (int c = 1; c < 8; ++c) {
        mfma_aa(acc0, arow[0][c], B[c]);
        mfma_aa(acc1, arow[1][c], B[c]);
      }
      mfma_fence(acc0, acc1);
      float r0 = __builtin_amdgcn_rcpf(acc0[0]);
      float r1 = __builtin_amdgcn_rcpf(acc0[1]);
      float r2 = __builtin_amdgcn_rcpf(acc0[2]);
      float r3 = __builtin_amdgcn_rcpf(acc0[3]);
      float r4 = __builtin_amdgcn_rcpf(acc1[0]);
      float r5 = __builtin_amdgcn_rcpf(acc1[1]);
      float r6 = __builtin_amdgcn_rcpf(acc1[2]);
      float r7 = __builtin_amdgcn_rcpf(acc1[3]);
      unsigned u0 = bf16pack(r0, r1), u1 = bf16pack(r2, r3);
      unsigned u2 = bf16pack(r4, r5), u3 = bf16pack(r6, r7);
      rsame = (u0 == oldR0.x) & (u1 == oldR0.y) & (u2 == oldR1.x) & (u3 == oldR1.y);
      if (m == 0) {  // rows 32w(+16)+4q..+3
        *(uint2*)&Rb16[32 * w + 4 * q] = make_uint2(u0, u1);
        *(uint2*)&Rb16[32 * w + 16 + 4 * q] = make_uint2(u2, u3);
      }
    }
    __syncthreads();

    // ---------- phase 2: t = V0^T_colslabs · R ; C = 1/t ----------
    {
      u32x4 B[8];
#pragma unroll
      for (int c = 0; c < 8; ++c) B[c] = *(const u32x4*)&Rb16[32 * c + 8 * q];
      uint2 oldC0 = *(const uint2*)&Cb16[32 * w + 4 * q];
      uint2 oldC1 = *(const uint2*)&Cb16[32 * w + 16 + 4 * q];
      f32x4 acc0, acc1;
      mfma_first(acc0, acol[0][0], B[0]);
      mfma_first(acc1, acol[1][0], B[0]);
#pragma unroll
      for (int c = 1; c < 8; ++c) {
        mfma_aa(acc0, acol[0][c], B[c]);
        mfma_aa(acc1, acol[1][c], B[c]);
      }
      mfma_fence(acc0, acc1);
      float c0 = __builtin_amdgcn_rcpf(acc0[0]);
      float c1 = __builtin_amdgcn_rcpf(acc0[1]);
      float c2 = __builtin_amdgcn_rcpf(acc0[2]);
      float c3 = __builtin_amdgcn_rcpf(acc0[3]);
      float c4 = __builtin_amdgcn_rcpf(acc1[0]);
      float c5 = __builtin_amdgcn_rcpf(acc1[1]);
      float c6 = __builtin_amdgcn_rcpf(acc1[2]);
      float c7 = __builtin_amdgcn_rcpf(acc1[3]);
      unsigned u0 = bf16pack(c0, c1), u1 = bf16pack(c2, c3);
      unsigned u2 = bf16pack(c4, c5), u3 = bf16pack(c6, c7);
      csame = (u0 == oldC0.x) & (u1 == oldC0.y) & (u2 == oldC1.x) & (u3 == oldC1.y);
      if (m == 0) {  // cols 32w(+16)+4q..+3
        *(uint2*)&Cb16[32 * w + 4 * q] = make_uint2(u0, u1);
        *(uint2*)&Cb16[32 * w + 16 + 4 * q] = make_uint2(u2, u3);
      }
      // Per-wave fixed-point flag (wave-uniform after __all).
      bool wconv = __all(rsame & csame) != 0;
      if (lane == 0) ((unsigned char*)Fl)[w] = wconv ? 1 : 0;
    }
    __syncthreads();
  }

  // ---------- finalize iteration (identity when converged): f32 scales ----
  {
    u32x4 B[8];
#pragma unroll
    for (int c = 0; c < 8; ++c) B[c] = *(const u32x4*)&Cb16[32 * c + 8 * q];
    f32x4 acc0, acc1;
    mfma_first(acc0, arow[0][0], B[0]);
    mfma_first(acc1, arow[1][0], B[0]);
#pragma unroll
    for (int c = 1; c < 8; ++c) {
      mfma_aa(acc0, arow[0][c], B[c]);
      mfma_aa(acc1, arow[1][c], B[c]);
    }
    mfma_fence(acc0, acc1);
    if (m == 0) {
      float r0 = __builtin_amdgcn_rcpf(acc0[0]);
      float r1 = __builtin_amdgcn_rcpf(acc0[1]);
      float r2 = __builtin_amdgcn_rcpf(acc0[2]);
      float r3 = __builtin_amdgcn_rcpf(acc0[3]);
      float r4 = __builtin_amdgcn_rcpf(acc1[0]);
      float r5 = __builtin_amdgcn_rcpf(acc1[1]);
      float r6 = __builtin_amdgcn_rcpf(acc1[2]);
      float r7 = __builtin_amdgcn_rcpf(acc1[3]);
      *(uint2*)&Rb16[32 * w + 4 * q] = make_uint2(bf16pack(r0, r1), bf16pack(r2, r3));
      *(uint2*)&Rb16[32 * w + 16 + 4 * q] = make_uint2(bf16pack(r4, r5), bf16pack(r6, r7));
      *(float4*)&Rb32[32 * w + 4 * q] = make_float4(r0, r1, r2, r3);
      *(float4*)&Rb32[32 * w + 16 + 4 * q] = make_float4(r4, r5, r6, r7);
    }
  }
  __syncthreads();
  {
    u32x4 B[8];
#pragma unroll
    for (int c = 0; c < 8; ++c) B[c] = *(const u32x4*)&Rb16[32 * c + 8 * q];
    f32x4 acc0, acc1;
    mfma_first(acc0, acol[0][0], B[0]);
    mfma_first(acc1, acol[1][0], B[0]);
#pragma unroll
    for (int c = 1; c < 8; ++c) {
      mfma_aa(acc0, acol[0][c], B[c]);
      mfma_aa(acc1, acol[1][c], B[c]);
    }
    mfma_fence(acc0, acc1);
    if (m == 0) {
      float c0 = __builtin_amdgcn_rcpf(acc0[0]);
      float c1 = __builtin_amdgcn_rcpf(acc0[1]);
      float c2 = __builtin_amdgcn_rcpf(acc0[2]);
      float c3 = __builtin_amdgcn_rcpf(acc0[3]);
      float c4 = __builtin_amdgcn_rcpf(acc1[0]);
      float c5 = __builtin_amdgcn_rcpf(acc1[1]);
      float c6 = __builtin_amdgcn_rcpf(acc1[2]);
      float c7 = __builtin_amdgcn_rcpf(acc1[3]);
      *(float4*)&Cb32[32 * w + 4 * q] = make_float4(c0, c1, c2, c3);
      *(float4*)&Cb32[32 * w + 16 + 4 * q] = make_float4(c4, c5, c6, c7);
    }
  }
  __syncthreads();

  // ---------- epilogue: out = diag(R32) · V0_bf16 · diag(C32) ----------
#pragma unroll
  for (int s = 0; s < 2; ++s) {
    const float Rm = Rb32[32 * w + 16 * s + m];
    float* dst = O + (size_t)(32 * w + 16 * s + m) * 256 + 8 * q;
#pragma unroll
    for (int c = 0; c < 8; ++c) {
      float4 c0 = *(const float4*)&Cb32[32 * c + 8 * q];
      float4 c1 = *(const float4*)&Cb32[32 * c + 8 * q + 4];
      u32x4 pk = arow[s][c];
      float4 o0, o1;
      o0.x = bflo(pk.x) * Rm * c0.x;
      o0.y = bfhi(pk.x) * Rm * c0.y;
      o0.z = bflo(pk.y) * Rm * c0.z;
      o0.w = bfhi(pk.y) * Rm * c0.w;
      o1.x = bflo(pk.z) * Rm * c1.x;
      o1.y = bfhi(pk.z) * Rm * c1.y;
      o1.z = bflo(pk.w) * Rm * c1.z;
      o1.w = bfhi(pk.w) * Rm * c1.w;
      *(float4*)(dst + 32 * c) = o0;
      *(float4*)(dst + 32 * c + 4) = o1;
    }
  }
}

extern "C" void kernel_launch(void* const* d_in, const int* in_sizes, int n_in,
                              void* d_out, int out_size, void* d_ws, size_t ws_size,
                              hipStream_t stream) {
  const float* alpha = (const float*)d_in[0];
  float* out = (float*)d_out;
  sinkhorn_mfma8c<<<dim3(16), dim3(512), 0, stream>>>(alpha, out);
}

// Round 10
// 185.749 us; speedup vs baseline: 1.0093x; 1.0093x over previous
//
#include <hip/hip_runtime.h>

#define N_ITER 100

typedef float f32x4 __attribute__((ext_vector_type(4)));
typedef unsigned u32x4 __attribute__((ext_vector_type(4)));

// RNE-pack two f32 into a dword of two bf16 (proven R7-R16: absmax 3.9e-3).
__device__ __forceinline__ unsigned bf16pack(float a, float b) {
  unsigned ua = __float_as_uint(a), ub = __float_as_uint(b);
  ua = (ua + 0x7FFFu + ((ua >> 16) & 1u)) >> 16;
  ub = (ub + 0x7FFFu + ((ub >> 16) & 1u)) >> 16;
  return ua | (ub << 16);
}
__device__ __forceinline__ float bflo(unsigned u) { return __uint_as_float(u << 16); }
__device__ __forceinline__ float bfhi(unsigned u) { return __uint_as_float(u & 0xFFFF0000u); }

// Force a value's virtual register into AGPR class AT DEFINITION (proven R13:
// kills the accvgpr copy tax; R6 re-proved it -- intrinsic version spilled to
// scratch, +3.7MB HBM round-trip, +23us).
__device__ __forceinline__ void pin_agpr(u32x4& x) {
  asm("" : "=a"(x) : "0"(x));
}

// MFMA with A + accumulator pinned to AGPRs, B in VGPRs (proven R13/R17).
__device__ __forceinline__ void mfma_first(f32x4& acc, const u32x4& a, const u32x4& b) {
  asm("s_nop 2\n\tv_mfma_f32_16x16x32_bf16 %0, %1, %2, 0"
      : "=&a"(acc) : "a"(a), "v"(b));
}
__device__ __forceinline__ void mfma_aa(f32x4& acc, const u32x4& a, const u32x4& b) {
  asm("v_mfma_f32_16x16x32_bf16 %0, %1, %2, %0"
      : "+a"(acc) : "a"(a), "v"(b));
}
__device__ __forceinline__ void mfma_fence(f32x4& acc0, f32x4& acc1) {
  asm volatile("s_nop 7\n\ts_nop 7\n\ts_nop 7" : "+a"(acc0), "+a"(acc1));
}

// Champion R0 structure (123us; every schedule restructure R1-R3/R5/R6
// regressed; R8 proved the clock is pinned ~700MHz -- heater didn't move it).
// R9 proved: bitwise period-1 fixed point never occurs in 99 iters, but
// absmax == exactly 1 bf16 ULP says the process IS numerically converged ->
// it is in a short limit cycle (period-2 rounding oscillation is the classic
// case; period-1 empirically excluded). Period-2 is exploitable BIT-EXACTLY:
// C_t = G(C_{t-1}) evolves autonomously; if C_t == C_{t-2} bitwise then all
// later C alternate, so the full run's C_98 (even index) equals whichever
// even-parity C we already hold. Detection: double-buffer C by parity
// (Cb16[it&1]); before overwriting, compare the new pack against the buffer
// content (= C_{t-2}); block-AND via per-wave flag bytes. On exit (or after
// 99 iters -- same path) the finalize pair recomputes R,C in f32 from
// Cb16[0] (== C_98 by periodicity), bit-identical to what iteration 99 of
// the full run computes. absmax must stay EXACTLY 0.00390625 (canary).
// Phase 1 is byte-identical to champion; phase 2 adds one early b64 read,
// 4 int compares in m==0 lanes, one __all, one flag byte (R9's +30us came
// from all-lane rcps -- removed; champion m==0-only tail restored).
__global__ __launch_bounds__(512)
__attribute__((amdgpu_waves_per_eu(2, 2)))
void sinkhorn_mfma8c2(const float* __restrict__ alpha, float* __restrict__ out) {
  __shared__ alignas(16) unsigned short Cb16[2][256];  // C double-buffered by parity
  __shared__ alignas(16) unsigned short Rb16[256];
  __shared__ alignas(16) float Cb32[256];
  __shared__ alignas(16) float Rb32[256];
  __shared__ alignas(8) unsigned Fl[2];  // 8 per-wave convergence flag bytes

  const int tid  = threadIdx.x;
  const int lane = tid & 63;
  const int w    = tid >> 6;   // wave 0..7
  const int m    = lane & 15;
  const int q    = lane >> 4;

  const size_t mbase = (size_t)blockIdx.x * (256 * 256);
  const float* A = alpha + mbase;
  float*       O = out + mbase;

  // arow[s][c] elem j <-> V0[32w+16s+m][32c+8q+j]
  // acol[s][c] elem j <-> V0[32c+8q+j][32w+16s+m]
  u32x4 arow[2][8];
  u32x4 acol[2][8];

#pragma unroll
  for (int s = 0; s < 2; ++s) {
    const float* rowp = A + (size_t)(32 * w + 16 * s + m) * 256 + 8 * q;
#pragma unroll
    for (int c = 0; c < 8; ++c) {
      float4 x0 = *(const float4*)(rowp + 32 * c);
      float4 x1 = *(const float4*)(rowp + 32 * c + 4);
      arow[s][c] = (u32x4){bf16pack(__expf(x0.x * 10.0f), __expf(x0.y * 10.0f)),
                           bf16pack(__expf(x0.z * 10.0f), __expf(x0.w * 10.0f)),
                           bf16pack(__expf(x1.x * 10.0f), __expf(x1.y * 10.0f)),
                           bf16pack(__expf(x1.z * 10.0f), __expf(x1.w * 10.0f))};
    }
    const float* colp = A + (size_t)(8 * q) * 256 + 32 * w + 16 * s + m;
#pragma unroll
    for (int c = 0; c < 8; ++c) {
      const float* p = colp + (size_t)(32 * c) * 256;
      acol[s][c] =
          (u32x4){bf16pack(__expf(p[0] * 10.0f), __expf(p[256] * 10.0f)),
                  bf16pack(__expf(p[512] * 10.0f), __expf(p[768] * 10.0f)),
                  bf16pack(__expf(p[1024] * 10.0f), __expf(p[1280] * 10.0f)),
                  bf16pack(__expf(p[1536] * 10.0f), __expf(p[1792] * 10.0f))};
    }
  }
  // Pin all persistent fragments into AGPRs (one-time, far from MFMAs).
#pragma unroll
  for (int s = 0; s < 2; ++s)
#pragma unroll
    for (int c = 0; c < 8; ++c) {
      pin_agpr(arow[s][c]);
      pin_agpr(acol[s][c]);
    }

  if (tid < 256) {
    Cb16[1][tid] = 0x3F80;  // C_{-1} = 1 (phase 1 of it=0 reads buffer 1)
    Cb16[0][tid] = 0;       // "C_{-2}": packs are never 0 -> first compare fails
  }
  if (tid < 2) Fl[tid] = 0;
  __syncthreads();

  for (int it = 0; it < N_ITER - 1; ++it) {
    // Convergence flags written during the previous iteration's phase 2.
    {
      uint2 fl = *(const uint2*)Fl;
      if (fl.x == 0x01010101u && fl.y == 0x01010101u) break;
    }

    // ---------- phase 1: s = V0_rowslabs · C_{it-1} ; R = 1/s ----------
    {
      const unsigned short* Cprev = Cb16[(it + 1) & 1];  // parity of it-1
      u32x4 B[8];
#pragma unroll
      for (int c = 0; c < 8; ++c) B[c] = *(const u32x4*)&Cprev[32 * c + 8 * q];
      f32x4 acc0, acc1;
      mfma_first(acc0, arow[0][0], B[0]);
      mfma_first(acc1, arow[1][0], B[0]);
#pragma unroll
      for (int c = 1; c < 8; ++c) {
        mfma_aa(acc0, arow[0][c], B[c]);
        mfma_aa(acc1, arow[1][c], B[c]);
      }
      mfma_fence(acc0, acc1);
      if (m == 0) {  // rows 32w(+16)+4q..+3
        float r0 = __builtin_amdgcn_rcpf(acc0[0]);
        float r1 = __builtin_amdgcn_rcpf(acc0[1]);
        float r2 = __builtin_amdgcn_rcpf(acc0[2]);
        float r3 = __builtin_amdgcn_rcpf(acc0[3]);
        float r4 = __builtin_amdgcn_rcpf(acc1[0]);
        float r5 = __builtin_amdgcn_rcpf(acc1[1]);
        float r6 = __builtin_amdgcn_rcpf(acc1[2]);
        float r7 = __builtin_amdgcn_rcpf(acc1[3]);
        *(uint2*)&Rb16[32 * w + 4 * q] = make_uint2(bf16pack(r0, r1), bf16pack(r2, r3));
        *(uint2*)&Rb16[32 * w + 16 + 4 * q] = make_uint2(bf16pack(r4, r5), bf16pack(r6, r7));
      }
    }
    __syncthreads();

    // ---------- phase 2: t = V0^T_colslabs · R ; C_it = 1/t ----------
    {
      u32x4 B[8];
#pragma unroll
      for (int c = 0; c < 8; ++c) B[c] = *(const u32x4*)&Rb16[32 * c + 8 * q];
      unsigned short* Ccur = Cb16[it & 1];  // holds C_{it-2}; will receive C_it
      uint2 oldC0 = *(const uint2*)&Ccur[32 * w + 4 * q];
      uint2 oldC1 = *(const uint2*)&Ccur[32 * w + 16 + 4 * q];
      asm volatile("" ::: "memory");  // pin oldC reads before the later writes
      f32x4 acc0, acc1;
      mfma_first(acc0, acol[0][0], B[0]);
      mfma_first(acc1, acol[1][0], B[0]);
#pragma unroll
      for (int c = 1; c < 8; ++c) {
        mfma_aa(acc0, acol[0][c], B[c]);
        mfma_aa(acc1, acol[1][c], B[c]);
      }
      mfma_fence(acc0, acc1);
      int pred = 1;
      if (m == 0) {  // cols 32w(+16)+4q..+3
        float c0 = __builtin_amdgcn_rcpf(acc0[0]);
        float c1 = __builtin_amdgcn_rcpf(acc0[1]);
        float c2 = __builtin_amdgcn_rcpf(acc0[2]);
        float c3 = __builtin_amdgcn_rcpf(acc0[3]);
        float c4 = __builtin_amdgcn_rcpf(acc1[0]);
        float c5 = __builtin_amdgcn_rcpf(acc1[1]);
        float c6 = __builtin_amdgcn_rcpf(acc1[2]);
        float c7 = __builtin_amdgcn_rcpf(acc1[3]);
        unsigned u0 = bf16pack(c0, c1), u1 = bf16pack(c2, c3);
        unsigned u2 = bf16pack(c4, c5), u3 = bf16pack(c6, c7);
        pred = (u0 == oldC0.x) & (u1 == oldC0.y) & (u2 == oldC1.x) & (u3 == oldC1.y);
        *(uint2*)&Ccur[32 * w + 4 * q] = make_uint2(u0, u1);
        *(uint2*)&Ccur[32 * w + 16 + 4 * q] = make_uint2(u2, u3);
      }
      bool wconv = __all(pred) != 0;  // C_it == C_{it-2} across this wave's cols
      if (lane == 0) ((unsigned char*)Fl)[w] = wconv ? 1 : 0;
    }
    __syncthreads();
  }

  // ---------- finalize (== iteration 99 of the full run, bit-exactly) ----
  // C_98 has even index -> it is the even-parity C = Cb16[0], whether we
  // exited early (periodicity) or ran all 99 loop iterations (it=98 wrote
  // Cb16[0] last). Compute R_99, C_99 in f32 for the epilogue.
  {
    u32x4 B[8];
#pragma unroll
    for (int c = 0; c < 8; ++c) B[c] = *(const u32x4*)&Cb16[0][32 * c + 8 * q];
    f32x4 acc0, acc1;
    mfma_first(acc0, arow[0][0], B[0]);
    mfma_first(acc1, arow[1][0], B[0]);
#pragma unroll
    for (int c = 1; c < 8; ++c) {
      mfma_aa(acc0, arow[0][c], B[c]);
      mfma_aa(acc1, arow[1][c], B[c]);
    }
    mfma_fence(acc0, acc1);
    if (m == 0) {
      float r0 = __builtin_amdgcn_rcpf(acc0[0]);
      float r1 = __builtin_amdgcn_rcpf(acc0[1]);
      float r2 = __builtin_amdgcn_rcpf(acc0[2]);
      float r3 = __builtin_amdgcn_rcpf(acc0[3]);
      float r4 = __builtin_amdgcn_rcpf(acc1[0]);
      float r5 = __builtin_amdgcn_rcpf(acc1[1]);
      float r6 = __builtin_amdgcn_rcpf(acc1[2]);
      float r7 = __builtin_amdgcn_rcpf(acc1[3]);
      *(uint2*)&Rb16[32 * w + 4 * q] = make_uint2(bf16pack(r0, r1), bf16pack(r2, r3));
      *(uint2*)&Rb16[32 * w + 16 + 4 * q] = make_uint2(bf16pack(r4, r5), bf16pack(r6, r7));
      *(float4*)&Rb32[32 * w + 4 * q] = make_float4(r0, r1, r2, r3);
      *(float4*)&Rb32[32 * w + 16 + 4 * q] = make_float4(r4, r5, r6, r7);
    }
  }
  __syncthreads();
  {
    u32x4 B[8];
#pragma unroll
    for (int c = 0; c < 8; ++c) B[c] = *(const u32x4*)&Rb16[32 * c + 8 * q];
    f32x4 acc0, acc1;
    mfma_first(acc0, acol[0][0], B[0]);
    mfma_first(acc1, acol[1][0], B[0]);
#pragma unroll
    for (int c = 1; c < 8; ++c) {
      mfma_aa(acc0, acol[0][c], B[c]);
      mfma_aa(acc1, acol[1][c], B[c]);
    }
    mfma_fence(acc0, acc1);
    if (m == 0) {
      float c0 = __builtin_amdgcn_rcpf(acc0[0]);
      float c1 = __builtin_amdgcn_rcpf(acc0[1]);
      float c2 = __builtin_amdgcn_rcpf(acc0[2]);
      float c3 = __builtin_amdgcn_rcpf(acc0[3]);
      float c4 = __builtin_amdgcn_rcpf(acc1[0]);
      float c5 = __builtin_amdgcn_rcpf(acc1[1]);
      float c6 = __builtin_amdgcn_rcpf(acc1[2]);
      float c7 = __builtin_amdgcn_rcpf(acc1[3]);
      *(float4*)&Cb32[32 * w + 4 * q] = make_float4(c0, c1, c2, c3);
      *(float4*)&Cb32[32 * w + 16 + 4 * q] = make_float4(c4, c5, c6, c7);
    }
  }
  __syncthreads();

  // ---------- epilogue: out = diag(R32) · V0_bf16 · diag(C32) ----------
#pragma unroll
  for (int s = 0; s < 2; ++s) {
    const float Rm = Rb32[32 * w + 16 * s + m];
    float* dst = O + (size_t)(32 * w + 16 * s + m) * 256 + 8 * q;
#pragma unroll
    for (int c = 0; c < 8; ++c) {
      float4 c0 = *(const float4*)&Cb32[32 * c + 8 * q];
      float4 c1 = *(const float4*)&Cb32[32 * c + 8 * q + 4];
      u32x4 pk = arow[s][c];
      float4 o0, o1;
      o0.x = bflo(pk.x) * Rm * c0.x;
      o0.y = bfhi(pk.x) * Rm * c0.y;
      o0.z = bflo(pk.y) * Rm * c0.z;
      o0.w = bfhi(pk.y) * Rm * c0.w;
      o1.x = bflo(pk.z) * Rm * c1.x;
      o1.y = bfhi(pk.z) * Rm * c1.y;
      o1.z = bflo(pk.w) * Rm * c1.z;
      o1.w = bfhi(pk.w) * Rm * c1.w;
      *(float4*)(dst + 32 * c) = o0;
      *(float4*)(dst + 32 * c + 4) = o1;
    }
  }
}

extern "C" void kernel_launch(void* const* d_in, const int* in_sizes, int n_in,
                              void* d_out, int out_size, void* d_ws, size_t ws_size,
                              hipStream_t stream) {
  const float* alpha = (const float*)d_in[0];
  float* out = (float*)d_out;
  sinkhorn_mfma8c2<<<dim3(16), dim3(512), 0, stream>>>(alpha, out);
}

// Round 11
// 184.916 us; speedup vs baseline: 1.0139x; 1.0045x over previous
//
#include <hip/hip_runtime.h>

#define N_ITER 100
#define EPS_CONV 0.010f

typedef float f32x4 __attribute__((ext_vector_type(4)));
typedef unsigned u32x4 __attribute__((ext_vector_type(4)));

// RNE-pack two f32 into a dword of two bf16 (proven R7-R16: absmax 3.9e-3).
__device__ __forceinline__ unsigned bf16pack(float a, float b) {
  unsigned ua = __float_as_uint(a), ub = __float_as_uint(b);
  ua = (ua + 0x7FFFu + ((ua >> 16) & 1u)) >> 16;
  ub = (ub + 0x7FFFu + ((ub >> 16) & 1u)) >> 16;
  return ua | (ub << 16);
}
__device__ __forceinline__ float bflo(unsigned u) { return __uint_as_float(u << 16); }
__device__ __forceinline__ float bfhi(unsigned u) { return __uint_as_float(u & 0xFFFF0000u); }

// Force a value's virtual register into AGPR class AT DEFINITION (proven R13;
// R6 re-proved: without pinning the allocator spills frags to scratch).
__device__ __forceinline__ void pin_agpr(u32x4& x) {
  asm("" : "=a"(x) : "0"(x));
}

// MFMA with A + accumulator pinned to AGPRs, B in VGPRs (proven R13/R17).
__device__ __forceinline__ void mfma_first(f32x4& acc, const u32x4& a, const u32x4& b) {
  asm("s_nop 2\n\tv_mfma_f32_16x16x32_bf16 %0, %1, %2, 0"
      : "=&a"(acc) : "a"(a), "v"(b));
}
__device__ __forceinline__ void mfma_aa(f32x4& acc, const u32x4& a, const u32x4& b) {
  asm("v_mfma_f32_16x16x32_bf16 %0, %1, %2, %0"
      : "+a"(acc) : "a"(a), "v"(b));
}
__device__ __forceinline__ void mfma_fence(f32x4& acc0, f32x4& acc1) {
  asm volatile("s_nop 7\n\ts_nop 7\n\ts_nop 7" : "+a"(acc0), "+a"(acc1));
}

// Champion R0 structure (123us; all schedule levers refuted R1-R6; clock
// pinned ~700MHz, R8; bitwise period-1/2 exits never fire, R9/R10).
// R11: the torch original's ANALYTIC convergence criterion -- exit when all
// column sums are within EPS of 1. Col-sum after phase 2's matvec is
// C_old[j]*t[j] (t = acc, pre-rcp), so the test costs 8 fmul+cmp in the
// m==0 tail plus one early b64 read of C_old (R10-proven pattern). Unlike
// the bitwise tests, this tolerates the bf16 ULP jitter that R9/R10 proved
// never settles. Flag load is issued inside phase 1 (hidden under B-loads/
// MFMAs; R10's +15us loop-head stall removed); break lands between phases;
// the finalize pair recomputes R,C in f32 (R10's bit-verified path -- when
// the loop runs all 99 iterations the output is bit-identical to champion).
__global__ __launch_bounds__(512)
__attribute__((amdgpu_waves_per_eu(2, 2)))
void sinkhorn_mfma8e(const float* __restrict__ alpha, float* __restrict__ out) {
  __shared__ alignas(16) unsigned short Cb16[256];
  __shared__ alignas(16) unsigned short Rb16[256];
  __shared__ alignas(16) float Cb32[256];
  __shared__ alignas(16) float Rb32[256];
  __shared__ alignas(8) unsigned Fl[2];  // 8 per-wave convergence flag bytes

  const int tid  = threadIdx.x;
  const int lane = tid & 63;
  const int w    = tid >> 6;   // wave 0..7
  const int m    = lane & 15;
  const int q    = lane >> 4;

  const size_t mbase = (size_t)blockIdx.x * (256 * 256);
  const float* A = alpha + mbase;
  float*       O = out + mbase;

  // arow[s][c] elem j <-> V0[32w+16s+m][32c+8q+j]
  // acol[s][c] elem j <-> V0[32c+8q+j][32w+16s+m]
  u32x4 arow[2][8];
  u32x4 acol[2][8];

#pragma unroll
  for (int s = 0; s < 2; ++s) {
    const float* rowp = A + (size_t)(32 * w + 16 * s + m) * 256 + 8 * q;
#pragma unroll
    for (int c = 0; c < 8; ++c) {
      float4 x0 = *(const float4*)(rowp + 32 * c);
      float4 x1 = *(const float4*)(rowp + 32 * c + 4);
      arow[s][c] = (u32x4){bf16pack(__expf(x0.x * 10.0f), __expf(x0.y * 10.0f)),
                           bf16pack(__expf(x0.z * 10.0f), __expf(x0.w * 10.0f)),
                           bf16pack(__expf(x1.x * 10.0f), __expf(x1.y * 10.0f)),
                           bf16pack(__expf(x1.z * 10.0f), __expf(x1.w * 10.0f))};
    }
    const float* colp = A + (size_t)(8 * q) * 256 + 32 * w + 16 * s + m;
#pragma unroll
    for (int c = 0; c < 8; ++c) {
      const float* p = colp + (size_t)(32 * c) * 256;
      acol[s][c] =
          (u32x4){bf16pack(__expf(p[0] * 10.0f), __expf(p[256] * 10.0f)),
                  bf16pack(__expf(p[512] * 10.0f), __expf(p[768] * 10.0f)),
                  bf16pack(__expf(p[1024] * 10.0f), __expf(p[1280] * 10.0f)),
                  bf16pack(__expf(p[1536] * 10.0f), __expf(p[1792] * 10.0f))};
    }
  }
  // Pin all persistent fragments into AGPRs (one-time, far from MFMAs).
#pragma unroll
  for (int s = 0; s < 2; ++s)
#pragma unroll
    for (int c = 0; c < 8; ++c) {
      pin_agpr(arow[s][c]);
      pin_agpr(acol[s][c]);
    }

  if (tid < 256) Cb16[tid] = 0x3F80;  // C = 1
  if (tid < 2) Fl[tid] = 0;
  __syncthreads();

  for (int it = 0; it < N_ITER - 1; ++it) {
    bool allconv;

    // ---------- phase 1: s = V0_rowslabs · C ; R = 1/s ----------
    {
      u32x4 B[8];
#pragma unroll
      for (int c = 0; c < 8; ++c) B[c] = *(const u32x4*)&Cb16[32 * c + 8 * q];
      // Convergence flags from the previous iteration's phase 2 -- issued
      // with the B loads, consumed only after the MFMAs (latency hidden).
      uint2 fl = *(const uint2*)Fl;
      f32x4 acc0, acc1;
      mfma_first(acc0, arow[0][0], B[0]);
      mfma_first(acc1, arow[1][0], B[0]);
#pragma unroll
      for (int c = 1; c < 8; ++c) {
        mfma_aa(acc0, arow[0][c], B[c]);
        mfma_aa(acc1, arow[1][c], B[c]);
      }
      mfma_fence(acc0, acc1);
      if (m == 0) {  // rows 32w(+16)+4q..+3
        float r0 = __builtin_amdgcn_rcpf(acc0[0]);
        float r1 = __builtin_amdgcn_rcpf(acc0[1]);
        float r2 = __builtin_amdgcn_rcpf(acc0[2]);
        float r3 = __builtin_amdgcn_rcpf(acc0[3]);
        float r4 = __builtin_amdgcn_rcpf(acc1[0]);
        float r5 = __builtin_amdgcn_rcpf(acc1[1]);
        float r6 = __builtin_amdgcn_rcpf(acc1[2]);
        float r7 = __builtin_amdgcn_rcpf(acc1[3]);
        *(uint2*)&Rb16[32 * w + 4 * q] = make_uint2(bf16pack(r0, r1), bf16pack(r2, r3));
        *(uint2*)&Rb16[32 * w + 16 + 4 * q] = make_uint2(bf16pack(r4, r5), bf16pack(r6, r7));
      }
      allconv = (fl.x == 0x01010101u) && (fl.y == 0x01010101u);
    }
    __syncthreads();
    if (allconv) break;  // converged: finalize recomputes this iterate in f32

    // ---------- phase 2: t = V0^T_colslabs · R ; C = 1/t ----------
    {
      u32x4 B[8];
#pragma unroll
      for (int c = 0; c < 8; ++c) B[c] = *(const u32x4*)&Rb16[32 * c + 8 * q];
      // Old C for the col-sum convergence test (early, off critical path).
      uint2 oc0 = *(const uint2*)&Cb16[32 * w + 4 * q];
      uint2 oc1 = *(const uint2*)&Cb16[32 * w + 16 + 4 * q];
      asm volatile("" ::: "memory");  // pin oc reads before the later writes
      f32x4 acc0, acc1;
      mfma_first(acc0, acol[0][0], B[0]);
      mfma_first(acc1, acol[1][0], B[0]);
#pragma unroll
      for (int c = 1; c < 8; ++c) {
        mfma_aa(acc0, acol[0][c], B[c]);
        mfma_aa(acc1, acol[1][c], B[c]);
      }
      mfma_fence(acc0, acc1);
      int pred = 1;
      if (m == 0) {  // cols 32w(+16)+4q..+3
        // torch-semantic convergence: current col sums = C_old * t (t = acc).
        float d0 = fabsf(bflo(oc0.x) * acc0[0] - 1.0f);
        float d1 = fabsf(bfhi(oc0.x) * acc0[1] - 1.0f);
        float d2 = fabsf(bflo(oc0.y) * acc0[2] - 1.0f);
        float d3 = fabsf(bfhi(oc0.y) * acc0[3] - 1.0f);
        float d4 = fabsf(bflo(oc1.x) * acc1[0] - 1.0f);
        float d5 = fabsf(bfhi(oc1.x) * acc1[1] - 1.0f);
        float d6 = fabsf(bflo(oc1.y) * acc1[2] - 1.0f);
        float d7 = fabsf(bfhi(oc1.y) * acc1[3] - 1.0f);
        float dm = fmaxf(fmaxf(fmaxf(d0, d1), fmaxf(d2, d3)),
                         fmaxf(fmaxf(d4, d5), fmaxf(d6, d7)));
        pred = (dm <= EPS_CONV);
        float c0 = __builtin_amdgcn_rcpf(acc0[0]);
        float c1 = __builtin_amdgcn_rcpf(acc0[1]);
        float c2 = __builtin_amdgcn_rcpf(acc0[2]);
        float c3 = __builtin_amdgcn_rcpf(acc0[3]);
        float c4 = __builtin_amdgcn_rcpf(acc1[0]);
        float c5 = __builtin_amdgcn_rcpf(acc1[1]);
        float c6 = __builtin_amdgcn_rcpf(acc1[2]);
        float c7 = __builtin_amdgcn_rcpf(acc1[3]);
        *(uint2*)&Cb16[32 * w + 4 * q] = make_uint2(bf16pack(c0, c1), bf16pack(c2, c3));
        *(uint2*)&Cb16[32 * w + 16 + 4 * q] = make_uint2(bf16pack(c4, c5), bf16pack(c6, c7));
      }
      bool wconv = __all(pred) != 0;
      if (lane == 0) ((unsigned char*)Fl)[w] = wconv ? 1 : 0;
    }
    __syncthreads();
  }

  // ---------- finalize (f32 scales; == champion's last iteration when the
  // loop runs to completion -- bit path verified in R10) ----------
  {
    u32x4 B[8];
#pragma unroll
    for (int c = 0; c < 8; ++c) B[c] = *(const u32x4*)&Cb16[32 * c + 8 * q];
    f32x4 acc0, acc1;
    mfma_first(acc0, arow[0][0], B[0]);
    mfma_first(acc1, arow[1][0], B[0]);
#pragma unroll
    for (int c = 1; c < 8; ++c) {
      mfma_aa(acc0, arow[0][c], B[c]);
      mfma_aa(acc1, arow[1][c], B[c]);
    }
    mfma_fence(acc0, acc1);
    if (m == 0) {
      float r0 = __builtin_amdgcn_rcpf(acc0[0]);
      float r1 = __builtin_amdgcn_rcpf(acc0[1]);
      float r2 = __builtin_amdgcn_rcpf(acc0[2]);
      float r3 = __builtin_amdgcn_rcpf(acc0[3]);
      float r4 = __builtin_amdgcn_rcpf(acc1[0]);
      float r5 = __builtin_amdgcn_rcpf(acc1[1]);
      float r6 = __builtin_amdgcn_rcpf(acc1[2]);
      float r7 = __builtin_amdgcn_rcpf(acc1[3]);
      *(uint2*)&Rb16[32 * w + 4 * q] = make_uint2(bf16pack(r0, r1), bf16pack(r2, r3));
      *(uint2*)&Rb16[32 * w + 16 + 4 * q] = make_uint2(bf16pack(r4, r5), bf16pack(r6, r7));
      *(float4*)&Rb32[32 * w + 4 * q] = make_float4(r0, r1, r2, r3);
      *(float4*)&Rb32[32 * w + 16 + 4 * q] = make_float4(r4, r5, r6, r7);
    }
  }
  __syncthreads();
  {
    u32x4 B[8];
#pragma unroll
    for (int c = 0; c < 8; ++c) B[c] = *(const u32x4*)&Rb16[32 * c + 8 * q];
    f32x4 acc0, acc1;
    mfma_first(acc0, acol[0][0], B[0]);
    mfma_first(acc1, acol[1][0], B[0]);
#pragma unroll
    for (int c = 1; c < 8; ++c) {
      mfma_aa(acc0, acol[0][c], B[c]);
      mfma_aa(acc1, acol[1][c], B[c]);
    }
    mfma_fence(acc0, acc1);
    if (m == 0) {
      float c0 = __builtin_amdgcn_rcpf(acc0[0]);
      float c1 = __builtin_amdgcn_rcpf(acc0[1]);
      float c2 = __builtin_amdgcn_rcpf(acc0[2]);
      float c3 = __builtin_amdgcn_rcpf(acc0[3]);
      float c4 = __builtin_amdgcn_rcpf(acc1[0]);
      float c5 = __builtin_amdgcn_rcpf(acc1[1]);
      float c6 = __builtin_amdgcn_rcpf(acc1[2]);
      float c7 = __builtin_amdgcn_rcpf(acc1[3]);
      *(float4*)&Cb32[32 * w + 4 * q] = make_float4(c0, c1, c2, c3);
      *(float4*)&Cb32[32 * w + 16 + 4 * q] = make_float4(c4, c5, c6, c7);
    }
  }
  __syncthreads();

  // ---------- epilogue: out = diag(R32) · V0_bf16 · diag(C32) ----------
#pragma unroll
  for (int s = 0; s < 2; ++s) {
    const float Rm = Rb32[32 * w + 16 * s + m];
    float* dst = O + (size_t)(32 * w + 16 * s + m) * 256 + 8 * q;
#pragma unroll
    for (int c = 0; c < 8; ++c) {
      float4 c0 = *(const float4*)&Cb32[32 * c + 8 * q];
      float4 c1 = *(const float4*)&Cb32[32 * c + 8 * q + 4];
      u32x4 pk = arow[s][c];
      float4 o0, o1;
      o0.x = bflo(pk.x) * Rm * c0.x;
      o0.y = bfhi(pk.x) * Rm * c0.y;
      o0.z = bflo(pk.y) * Rm * c0.z;
      o0.w = bfhi(pk.y) * Rm * c0.w;
      o1.x = bflo(pk.z) * Rm * c1.x;
      o1.y = bfhi(pk.z) * Rm * c1.y;
      o1.z = bflo(pk.w) * Rm * c1.z;
      o1.w = bfhi(pk.w) * Rm * c1.w;
      *(float4*)(dst + 32 * c) = o0;
      *(float4*)(dst + 32 * c + 4) = o1;
    }
  }
}

extern "C" void kernel_launch(void* const* d_in, const int* in_sizes, int n_in,
                              void* d_out, int out_size, void* d_ws, size_t ws_size,
                              hipStream_t stream) {
  const float* alpha = (const float*)d_in[0];
  float* out = (float*)d_out;
  sinkhorn_mfma8e<<<dim3(16), dim3(512), 0, stream>>>(alpha, out);
}

// Round 12
// 169.114 us; speedup vs baseline: 1.1086x; 1.0934x over previous
//
#include <hip/hip_runtime.h>

#define N_ITER 100

typedef float f32x4 __attribute__((ext_vector_type(4)));
typedef unsigned u32x4 __attribute__((ext_vector_type(4)));

// RNE-pack two f32 into a dword of two bf16 (proven R7-R16: absmax 3.9e-3).
__device__ __forceinline__ unsigned bf16pack(float a, float b) {
  unsigned ua = __float_as_uint(a), ub = __float_as_uint(b);
  ua = (ua + 0x7FFFu + ((ua >> 16) & 1u)) >> 16;
  ub = (ub + 0x7FFFu + ((ub >> 16) & 1u)) >> 16;
  return ua | (ub << 16);
}
__device__ __forceinline__ float bflo(unsigned u) { return __uint_as_float(u << 16); }
__device__ __forceinline__ float bfhi(unsigned u) { return __uint_as_float(u & 0xFFFF0000u); }

// Force a value's virtual register into AGPR class AT DEFINITION (proven R13:
// kills the accvgpr copy tax without the R11/R12 asm-boundary hazards).
__device__ __forceinline__ void pin_agpr(u32x4& x) {
  asm("" : "=a"(x) : "0"(x));
}

// MFMA with A + accumulator pinned to AGPRs, B in VGPRs.
// Hazard audit (R17): interior MFMAs read only B (ds_read-written, waitcnt-
// protected -- not a VALU write), A (AGPR, pinned far away) and acc (MFMA->
// MFMA same-pipe chain, HW-interlocked). So no entry s_nop needed inside the
// chain; keep one s_nop 2 at chain start as insurance against compiler-
// scheduled VALU at block entry, and the proven 24-cyc data-tied exit fence
// before any VALU (v_accvgpr_read) touches the MFMA destination.
__device__ __forceinline__ void mfma_first(f32x4& acc, const u32x4& a, const u32x4& b) {
  asm("s_nop 2\n\tv_mfma_f32_16x16x32_bf16 %0, %1, %2, 0"
      : "=&a"(acc) : "a"(a), "v"(b));
}
__device__ __forceinline__ void mfma_aa(f32x4& acc, const u32x4& a, const u32x4& b) {
  asm("v_mfma_f32_16x16x32_bf16 %0, %1, %2, %0"
      : "+a"(acc) : "a"(a), "v"(b));
}
__device__ __forceinline__ void mfma_fence(f32x4& acc0, f32x4& acc1) {
  asm volatile("s_nop 7\n\ts_nop 7\n\ts_nop 7" : "+a"(acc0), "+a"(acc1));
}

// One block (512 threads = 8 waves) per matrix (R13 structure, proven best:
// 123 us). Wave w owns rows [32w,32w+32) and cols [32w,32w+32) of V0 (bf16
// A-frags pinned in AGPRs). Scales broadcast through the MFMA B operand (all
// 16 n-cols identical -> D reg r = sum for row/col 4q+r, any lane). Floors:
// LDS 128 ds_read_b128/CU/iter ~1536 cyc; MFMA 64/SIMD/iter ~310 cyc.
// Layouts (m89-verified): A elem j <-> A[m=lane&15][k=8q+j]; D reg r <-> row
// 4q+r, col=lane&15.
// Session scoreboard (R1-R11): every structural lever measured and refuted --
// wave count (R1), chain depth (R2), tail shape (R3), LDS prefetch (R4,
// hazard), VGPR-A (R5/R6, spill tax), clock heater (R8, clock pinned
// ~700MHz), bitwise period-1/2 exits (R9/R10, never fire), analytic
// early-exit (R11, fires ~iter 95, overhead-negative). This is the cycle
// floor of the 200-serial-phase structure at the pinned clock.
__global__ __launch_bounds__(512)
__attribute__((amdgpu_waves_per_eu(2, 2)))
void sinkhorn_mfma8f(const float* __restrict__ alpha, float* __restrict__ out) {
  __shared__ alignas(16) unsigned short Cb16[256];
  __shared__ alignas(16) unsigned short Rb16[256];
  __shared__ alignas(16) float Cb32[256];
  __shared__ alignas(16) float Rb32[256];

  const int tid  = threadIdx.x;
  const int lane = tid & 63;
  const int w    = tid >> 6;   // wave 0..7
  const int m    = lane & 15;
  const int q    = lane >> 4;

  const size_t mbase = (size_t)blockIdx.x * (256 * 256);
  const float* A = alpha + mbase;
  float*       O = out + mbase;

  // arow[s][c] elem j <-> V0[32w+16s+m][32c+8q+j]
  // acol[s][c] elem j <-> V0[32c+8q+j][32w+16s+m]
  u32x4 arow[2][8];
  u32x4 acol[2][8];

#pragma unroll
  for (int s = 0; s < 2; ++s) {
    const float* rowp = A + (size_t)(32 * w + 16 * s + m) * 256 + 8 * q;
#pragma unroll
    for (int c = 0; c < 8; ++c) {
      float4 x0 = *(const float4*)(rowp + 32 * c);
      float4 x1 = *(const float4*)(rowp + 32 * c + 4);
      arow[s][c] = (u32x4){bf16pack(__expf(x0.x * 10.0f), __expf(x0.y * 10.0f)),
                           bf16pack(__expf(x0.z * 10.0f), __expf(x0.w * 10.0f)),
                           bf16pack(__expf(x1.x * 10.0f), __expf(x1.y * 10.0f)),
                           bf16pack(__expf(x1.z * 10.0f), __expf(x1.w * 10.0f))};
    }
    const float* colp = A + (size_t)(8 * q) * 256 + 32 * w + 16 * s + m;
#pragma unroll
    for (int c = 0; c < 8; ++c) {
      const float* p = colp + (size_t)(32 * c) * 256;
      acol[s][c] =
          (u32x4){bf16pack(__expf(p[0] * 10.0f), __expf(p[256] * 10.0f)),
                  bf16pack(__expf(p[512] * 10.0f), __expf(p[768] * 10.0f)),
                  bf16pack(__expf(p[1024] * 10.0f), __expf(p[1280] * 10.0f)),
                  bf16pack(__expf(p[1536] * 10.0f), __expf(p[1792] * 10.0f))};
    }
  }
  // Pin all persistent fragments into AGPRs (one-time, far from MFMAs).
#pragma unroll
  for (int s = 0; s < 2; ++s)
#pragma unroll
    for (int c = 0; c < 8; ++c) {
      pin_agpr(arow[s][c]);
      pin_agpr(acol[s][c]);
    }

  if (tid < 256) Cb16[tid] = 0x3F80;  // C = 1
  __syncthreads();

  for (int it = 0; it < N_ITER; ++it) {
    const bool last = (it == N_ITER - 1);

    // ---------- phase 1: s = V0_rowslabs · C ; R = 1/s ----------
    {
      u32x4 B[8];
#pragma unroll
      for (int c = 0; c < 8; ++c) B[c] = *(const u32x4*)&Cb16[32 * c + 8 * q];
      f32x4 acc0, acc1;
      mfma_first(acc0, arow[0][0], B[0]);
      mfma_first(acc1, arow[1][0], B[0]);
#pragma unroll
      for (int c = 1; c < 8; ++c) {
        mfma_aa(acc0, arow[0][c], B[c]);
        mfma_aa(acc1, arow[1][c], B[c]);
      }
      mfma_fence(acc0, acc1);
      if (m == 0) {  // rows 32w(+16)+4q..+3
        float r0 = __builtin_amdgcn_rcpf(acc0[0]);
        float r1 = __builtin_amdgcn_rcpf(acc0[1]);
        float r2 = __builtin_amdgcn_rcpf(acc0[2]);
        float r3 = __builtin_amdgcn_rcpf(acc0[3]);
        float r4 = __builtin_amdgcn_rcpf(acc1[0]);
        float r5 = __builtin_amdgcn_rcpf(acc1[1]);
        float r6 = __builtin_amdgcn_rcpf(acc1[2]);
        float r7 = __builtin_amdgcn_rcpf(acc1[3]);
        *(uint2*)&Rb16[32 * w + 4 * q] = make_uint2(bf16pack(r0, r1), bf16pack(r2, r3));
        *(uint2*)&Rb16[32 * w + 16 + 4 * q] = make_uint2(bf16pack(r4, r5), bf16pack(r6, r7));
        if (last) {
          *(float4*)&Rb32[32 * w + 4 * q] = make_float4(r0, r1, r2, r3);
          *(float4*)&Rb32[32 * w + 16 + 4 * q] = make_float4(r4, r5, r6, r7);
        }
      }
    }
    __syncthreads();

    // ---------- phase 2: t = V0^T_colslabs · R ; C = 1/t ----------
    {
      u32x4 B[8];
#pragma unroll
      for (int c = 0; c < 8; ++c) B[c] = *(const u32x4*)&Rb16[32 * c + 8 * q];
      f32x4 acc0, acc1;
      mfma_first(acc0, acol[0][0], B[0]);
      mfma_first(acc1, acol[1][0], B[0]);
#pragma unroll
      for (int c = 1; c < 8; ++c) {
        mfma_aa(acc0, acol[0][c], B[c]);
        mfma_aa(acc1, acol[1][c], B[c]);
      }
      mfma_fence(acc0, acc1);
      if (m == 0) {  // cols 32w(+16)+4q..+3
        float c0 = __builtin_amdgcn_rcpf(acc0[0]);
        float c1 = __builtin_amdgcn_rcpf(acc0[1]);
        float c2 = __builtin_amdgcn_rcpf(acc0[2]);
        float c3 = __builtin_amdgcn_rcpf(acc0[3]);
        float c4 = __builtin_amdgcn_rcpf(acc1[0]);
        float c5 = __builtin_amdgcn_rcpf(acc1[1]);
        float c6 = __builtin_amdgcn_rcpf(acc1[2]);
        float c7 = __builtin_amdgcn_rcpf(acc1[3]);
        *(uint2*)&Cb16[32 * w + 4 * q] = make_uint2(bf16pack(c0, c1), bf16pack(c2, c3));
        *(uint2*)&Cb16[32 * w + 16 + 4 * q] = make_uint2(bf16pack(c4, c5), bf16pack(c6, c7));
        if (last) {
          *(float4*)&Cb32[32 * w + 4 * q] = make_float4(c0, c1, c2, c3);
          *(float4*)&Cb32[32 * w + 16 + 4 * q] = make_float4(c4, c5, c6, c7);
        }
      }
    }
    __syncthreads();
  }

  // ---------- epilogue: out = diag(R32) · V0_bf16 · diag(C32) ----------
#pragma unroll
  for (int s = 0; s < 2; ++s) {
    const float Rm = Rb32[32 * w + 16 * s + m];
    float* dst = O + (size_t)(32 * w + 16 * s + m) * 256 + 8 * q;
#pragma unroll
    for (int c = 0; c < 8; ++c) {
      float4 c0 = *(const float4*)&Cb32[32 * c + 8 * q];
      float4 c1 = *(const float4*)&Cb32[32 * c + 8 * q + 4];
      u32x4 pk = arow[s][c];
      float4 o0, o1;
      o0.x = bflo(pk.x) * Rm * c0.x;
      o0.y = bfhi(pk.x) * Rm * c0.y;
      o0.z = bflo(pk.y) * Rm * c0.z;
      o0.w = bfhi(pk.y) * Rm * c0.w;
      o1.x = bflo(pk.z) * Rm * c1.x;
      o1.y = bfhi(pk.z) * Rm * c1.y;
      o1.z = bflo(pk.w) * Rm * c1.z;
      o1.w = bfhi(pk.w) * Rm * c1.w;
      *(float4*)(dst + 32 * c) = o0;
      *(float4*)(dst + 32 * c + 4) = o1;
    }
  }
}

extern "C" void kernel_launch(void* const* d_in, const int* in_sizes, int n_in,
                              void* d_out, int out_size, void* d_ws, size_t ws_size,
                              hipStream_t stream) {
  const float* alpha = (const float*)d_in[0];
  float* out = (float*)d_out;
  sinkhorn_mfma8f<<<dim3(16), dim3(512), 0, stream>>>(alpha, out);
}